// Round 1
// baseline (346.976 us; speedup 1.0000x reference)
//
#include <hip/hip_runtime.h>
#include <math.h>

// Problem constants (fixed by reference)
#define BS_TOT 32768      // B*S = 16*2048
#define IN_DIM 768
#define G_N 2
#define V_N 320
#define D_N 384
#define OUT_N 768
#define EPS_F 1e-10f

typedef _Float16 f16x8 __attribute__((ext_vector_type(8)));
typedef float    f32x16 __attribute__((ext_vector_type(16)));

#define GLOBAL_LOAD_LDS16(gaddr, laddr)                                        \
  __builtin_amdgcn_global_load_lds(                                            \
      (const __attribute__((address_space(1))) unsigned int*)(gaddr),          \
      (__attribute__((address_space(3))) unsigned int*)(laddr), 16, 0, 0)

// ---------------------------------------------------------------------------
// Kernel 0: split W_logits [384][320] fp32 into two f16 planes, tile-ordered
// for KSTEP=16 global_load_lds staging: unit u = ((t*2+plane)*2+kh)*320+v,
// k = t*16 + kh*8 + j. Plane 0 = f16(w); plane 1 = f16(4096*(w - plane0)).
// ---------------------------------------------------------------------------
__global__ __launch_bounds__(256) void prep_w(
    const float* __restrict__ Wl, _Float16* __restrict__ Wp)
{
    int e = blockIdx.x * 256 + threadIdx.x;
    if (e >= D_N * V_N) return;
    int k = e / V_N, v = e - k * V_N;
    int t = k >> 4, kh = (k >> 3) & 1, j = k & 7;
    float w = Wl[e];
    _Float16 a = (_Float16)w;
    float r = (w - (float)a) * 4096.f;
    Wp[((size_t)((t * 2 + 0) * 2 + kh) * V_N + v) * 8 + j] = a;
    Wp[((size_t)((t * 2 + 1) * 2 + kh) * V_N + v) * 8 + j] = (_Float16)r;
}

// ---------------------------------------------------------------------------
// Kernel A: P[g*320+v][o] = sum_d codebooks[g][v][d] * W_out[g*384+d][o]
// (unchanged — validated)
// ---------------------------------------------------------------------------
__global__ __launch_bounds__(256) void precompute_P(
    const float* __restrict__ cb, const float* __restrict__ Wo,
    float* __restrict__ P)
{
    const int tid = threadIdx.x;
    const int c0  = blockIdx.x * 256;
    const int r0  = blockIdx.y * 8;
    const int g   = r0 / V_N;
    __shared__ float As[8][D_N];
    {
        const float4* src = (const float4*)(cb + (size_t)r0 * D_N);
        float4* dst = (float4*)(&As[0][0]);
        #pragma unroll
        for (int p = 0; p < 3; ++p) dst[tid + p * 256] = src[tid + p * 256];
    }
    __syncthreads();
    float acc[8];
    #pragma unroll
    for (int i = 0; i < 8; ++i) acc[i] = 0.f;
    const float* wp = Wo + ((size_t)g * D_N) * OUT_N + c0 + tid;
    for (int d = 0; d < D_N; d += 4) {
        float w0 = wp[(size_t)(d + 0) * OUT_N];
        float w1 = wp[(size_t)(d + 1) * OUT_N];
        float w2 = wp[(size_t)(d + 2) * OUT_N];
        float w3 = wp[(size_t)(d + 3) * OUT_N];
        #pragma unroll
        for (int i = 0; i < 8; ++i) {
            float4 a = *(const float4*)&As[i][d];
            acc[i] = fmaf(a.x, w0, acc[i]);
            acc[i] = fmaf(a.y, w1, acc[i]);
            acc[i] = fmaf(a.z, w2, acc[i]);
            acc[i] = fmaf(a.w, w3, acc[i]);
        }
    }
    #pragma unroll
    for (int i = 0; i < 8; ++i)
        P[(size_t)(r0 + i) * OUT_N + c0 + tid] = acc[i];
}

// ---------------------------------------------------------------------------
// Kernel B (fused): per block = 64 rows, BOTH groups sequentially.
// K-loop: KSTEP=16, double-buffered LDS (B 2x20KB + A 2x4KB), issue-early
// staging (stage t+1 before compute t, one barrier/iter) so global->LDS
// latency hides under MFMA+ds_read instead of a drain-before-compute stall.
// Epilogue per group: gumbel + argmax -> sFin[g]. After both groups: fused
// gather  out[row] = P[i0] + P[320+i1] + b_out  (gather_out kernel removed).
// ---------------------------------------------------------------------------
__global__ __launch_bounds__(256, 2) void logits_fused(
    const float* __restrict__ z, const float* __restrict__ noise,
    const f16x8* __restrict__ Wp, const float* __restrict__ bl,
    const float* __restrict__ P, const float* __restrict__ bo,
    float* __restrict__ out)
{
    const int tid  = threadIdx.x;
    const int m0   = blockIdx.x * 64;
    const int ln   = tid & 63;
    const int wv   = tid >> 6;
    const int wrow = wv >> 1;      // 0..1: M half
    const int wcol = wv & 1;       // 0..1: N half (160 cols)
    const int lh   = ln >> 5;
    const int l5   = ln & 31;

    __shared__ f16x8 BsV[2][1280];   // [buf][(plane*2+kh)*320 + v], 40960 B
    __shared__ f16x8 AsV[2][256];    // [buf][(plane*2+kh)*64 + row], 8192 B
    __shared__ float sVal[2][64];
    __shared__ int   sIdx[2][64];
    __shared__ int   sFin[2][64];    // final argmax per group

    const int arow = wrow * 32 + l5;   // fragment row in block
    const int bcol = wcol * 160 + l5;  // fragment col base

    // A producer mapping: threads 0..127 -> (row = tid&63, kh = tid>>6)
    const int  prow  = tid & 63;
    const int  pkh   = tid >> 6;
    const bool aprod = (tid < 128);

    float blv[5];
    #pragma unroll
    for (int nf = 0; nf < 5; ++nf) blv[nf] = bl[wcol * 160 + nf * 32 + l5];

    for (int g = 0; g < 2; ++g) {
        f32x16 accM[5], accC[5];
        #pragma unroll
        for (int nf = 0; nf < 5; ++nf)
            #pragma unroll
            for (int i = 0; i < 16; ++i) { accM[nf][i] = 0.f; accC[nf][i] = 0.f; }

        const float* zb = z + (size_t)(m0 + prow) * IN_DIM + g * D_N + pkh * 8;
        float4 az0 = {0.f, 0.f, 0.f, 0.f}, az1 = {0.f, 0.f, 0.f, 0.f};

        // -------- prologue: stage t=0 into buf0, prefetch A regs for t=1 ----
        #pragma unroll
        for (int p = 0; p < 5; ++p)
            GLOBAL_LOAD_LDS16(Wp + (wv * 5 + p) * 64 + ln,
                              &BsV[0][(wv * 5 + p) * 64]);
        if (aprod) {
            float4 q0 = *(const float4*)(zb);
            float4 q1 = *(const float4*)(zb + 4);
            float x[8] = {q0.x, q0.y, q0.z, q0.w, q1.x, q1.y, q1.z, q1.w};
            f16x8 h1, h2;
            #pragma unroll
            for (int i = 0; i < 8; ++i) {
                _Float16 a = (_Float16)x[i];
                float r = (x[i] - (float)a) * 4096.f;
                h1[i] = a;
                h2[i] = (_Float16)r;
            }
            AsV[0][(0 + pkh) * 64 + prow] = h1;
            AsV[0][(2 + pkh) * 64 + prow] = h2;
            az0 = *(const float4*)(zb + 16);
            az1 = *(const float4*)(zb + 20);
        }
        __syncthreads();   // B[0] resident, A[0] visible

        // -------- main loop: issue-early, double-buffered, 1 barrier/iter ---
        #pragma unroll 2
        for (int t = 0; t < 24; ++t) {
            const int cb  = t & 1;
            const int nb  = cb ^ 1;
            const int nxt = t + 1;
            if (nxt < 24) {
                // issue next B tile (stays in flight across the compute phase)
                #pragma unroll
                for (int p = 0; p < 5; ++p)
                    GLOBAL_LOAD_LDS16(Wp + (size_t)nxt * 1280 + (wv * 5 + p) * 64 + ln,
                                      &BsV[nb][(wv * 5 + p) * 64]);
                if (aprod) {
                    // split A regs (prefetched last iter) -> LDS, then prefetch
                    float x[8] = {az0.x, az0.y, az0.z, az0.w,
                                  az1.x, az1.y, az1.z, az1.w};
                    f16x8 h1, h2;
                    #pragma unroll
                    for (int i = 0; i < 8; ++i) {
                        _Float16 a = (_Float16)x[i];
                        float r = (x[i] - (float)a) * 4096.f;
                        h1[i] = a;
                        h2[i] = (_Float16)r;
                    }
                    AsV[nb][(0 + pkh) * 64 + prow] = h1;
                    AsV[nb][(2 + pkh) * 64 + prow] = h2;
                    if (nxt + 1 < 24) {
                        az0 = *(const float4*)(zb + (size_t)(nxt + 1) * 16);
                        az1 = *(const float4*)(zb + (size_t)(nxt + 1) * 16 + 4);
                    }
                }
            }
            // compute tile t from buf cb
            f16x8 A0 = AsV[cb][(0 + lh) * 64 + arow];
            f16x8 A1 = AsV[cb][(2 + lh) * 64 + arow];
            #pragma unroll
            for (int nf = 0; nf < 5; ++nf) {
                f16x8 B0 = BsV[cb][(0 + lh) * 320 + bcol + nf * 32];
                f16x8 B1 = BsV[cb][(2 + lh) * 320 + bcol + nf * 32];
                accM[nf] = __builtin_amdgcn_mfma_f32_32x32x16_f16(A0, B0, accM[nf], 0, 0, 0);
                accC[nf] = __builtin_amdgcn_mfma_f32_32x32x16_f16(A0, B1, accC[nf], 0, 0, 0);
                accC[nf] = __builtin_amdgcn_mfma_f32_32x32x16_f16(A1, B0, accC[nf], 0, 0, 0);
            }
            __syncthreads();   // drains B[nxt] DMA + A[nxt] writes; frees buf cb
        }

        // -------- epilogue: logits = main + 2^-12*cross + bl + gumbel; argmax
        #pragma unroll
        for (int r = 0; r < 16; ++r) {
            const int rowloc = (r & 3) + 8 * (r >> 2) + 4 * lh;   // C/D row map
            const int grow   = m0 + wrow * 32 + rowloc;
            const float* np_ = noise + ((size_t)grow * G_N + g) * V_N + wcol * 160 + l5;
            float best = -INFINITY; int bi = 0;
            #pragma unroll
            for (int nf = 0; nf < 5; ++nf) {
                float u   = np_[nf * 32];
                float gum = -__logf(-__logf(u + EPS_F) + EPS_F);
                float v   = accM[nf][r] + 2.44140625e-4f * accC[nf][r] + blv[nf] + gum;
                int   c   = wcol * 160 + nf * 32 + l5;
                if (v > best) { best = v; bi = c; }
            }
            #pragma unroll
            for (int off = 1; off < 32; off <<= 1) {   // reduce within 32-lane half
                float ov = __shfl_xor(best, off);
                int   oi = __shfl_xor(bi, off);
                if (ov > best || (ov == best && oi < bi)) { best = ov; bi = oi; }
            }
            if (l5 == 0) {
                sVal[wcol][wrow * 32 + rowloc] = best;
                sIdx[wcol][wrow * 32 + rowloc] = bi;
            }
        }
        __syncthreads();
        if (tid < 64) {
            float v0 = sVal[0][tid], v1 = sVal[1][tid];
            int   i0 = sIdx[0][tid], i1 = sIdx[1][tid];
            sFin[g][tid] = (v1 > v0 || (v1 == v0 && i1 < i0)) ? i1 : i0;
        }
        // next pass's prologue barrier orders sFin/sVal reuse
    }
    __syncthreads();   // sFin[0..1] visible to all

    // -------- fused gather: out[row] = P[i0] + P[320+i1] + b_out -----------
    const float4* Pv  = (const float4*)P;
    const float4* bov = (const float4*)bo;
    #pragma unroll 4
    for (int p = 0; p < 48; ++p) {
        int f  = p * 256 + tid;        // 64 rows * 192 float4 = 12288 slots
        int rl = f / 192;
        int c4 = f - rl * 192;
        int i0 = sFin[0][rl];
        int i1 = sFin[1][rl];
        float4 a  = Pv[(size_t)i0 * 192 + c4];
        float4 b2 = Pv[(size_t)(V_N + i1) * 192 + c4];
        float4 c  = bov[c4];
        float4 r;
        r.x = a.x + b2.x + c.x;
        r.y = a.y + b2.y + c.y;
        r.z = a.z + b2.z + c.z;
        r.w = a.w + b2.w + c.w;
        ((float4*)(out + (size_t)(m0 + rl) * OUT_N))[c4] = r;
    }
}

// ---------------------------------------------------------------------------
extern "C" void kernel_launch(void* const* d_in, const int* in_sizes, int n_in,
                              void* d_out, int out_size, void* d_ws, size_t ws_size,
                              hipStream_t stream)
{
    const float* z     = (const float*)d_in[0];
    const float* noise = (const float*)d_in[1];
    const float* Wl    = (const float*)d_in[2];
    const float* bl    = (const float*)d_in[3];
    const float* cb    = (const float*)d_in[4];
    const float* Wo    = (const float*)d_in[5];
    const float* bo    = (const float*)d_in[6];
    float* out = (float*)d_out;

    // ws layout: P (1,966,080 B) | Wp f16 planes (491,520 B)
    float*     P  = (float*)d_ws;
    _Float16*  Wp = (_Float16*)((char*)d_ws + 1966080);

    prep_w<<<(D_N * V_N + 255) / 256, 256, 0, stream>>>(Wl, Wp);

    dim3 gA(OUT_N / 256, (G_N * V_N) / 8);
    precompute_P<<<gA, 256, 0, stream>>>(cb, Wo, P);

    logits_fused<<<BS_TOT / 64, 256, 0, stream>>>(
        z, noise, (const f16x8*)Wp, bl, P, bo, out);
}